// Round 6
// baseline (100.215 us; speedup 1.0000x reference)
//
#include <hip/hip_runtime.h>
#include <hip/hip_bf16.h>
#include <stdint.h>

#define B_   4
#define H_   56
#define W_   56
#define C_   256
#define CR   64
#define G_   16
#define CG   16
#define KS   7
#define KK   49
#define PADR 3
#define NPX  (B_*H_*W_)   // 12544

typedef __attribute__((ext_vector_type(8))) short bf16x8;
typedef __attribute__((ext_vector_type(4))) float f32x4;
typedef __attribute__((ext_vector_type(2))) float f32x2;

__device__ __forceinline__ uint32_t f2bf(float f) {          // RNE fp32->bf16 bits
    uint32_t x = __float_as_uint(f);
    return (x + 0x7fffu + ((x >> 16) & 1u)) >> 16;
}
__device__ __forceinline__ uint32_t pkbf(float a, float b) { // packed RNE: v_cvt_pk_bf16_f32
    union { __hip_bfloat162 h; uint32_t u; } c;
    c.h = __float22bfloat162_rn(make_float2(a, b));
    return c.u;                                              // a lo16, b hi16
}
__device__ __forceinline__ float blo(uint32_t w) { return __uint_as_float(w << 16); }
__device__ __forceinline__ float bhi(uint32_t w) { return __uint_as_float(w & 0xffff0000u); }

union U4V { uint4 u; bf16x8 v; };

// ---------- K1: r = relu(bn(x @ w_reduce)) via MFMA + emit x as bf16 ----------
// B-frag (mfma_f32_16x16x32_bf16): lane holds B[k=(lane>>4)*8+j][n=lane&15], j=0..7.
// B-frag table for w_reduce built in LDS per block (replaces old k0 prepack).
__global__ __launch_bounds__(256) void k1_reduce(
        const float* __restrict__ x, const float* __restrict__ wr,
        const float* __restrict__ gamma, const float* __restrict__ beta,
        const float* __restrict__ mean, const float* __restrict__ var,
        uint16_t* __restrict__ r, uint16_t* __restrict__ xbf) {
    __shared__ __align__(16) uint16_t wrl[16384];   // 32 KB: 8kb x 4nb x 64lane x 8
    int tid = threadIdx.x;
    int lane = tid & 63, w = tid >> 6;

    // ---- cooperative B-frag build: 2048 runs of 8 bf16, 8 runs/thread ----
    #pragma unroll
    for (int s = 0; s < 8; ++s) {
        int run = tid + s * 256;                    // = kb*256 + nb*64 + rl
        int rl = run & 63, nb = (run >> 6) & 3, kb = run >> 8;
        int n = nb * 16 + (rl & 15);
        int kbase = kb * 32 + (rl >> 4) * 8;
        uint32_t pk0 = pkbf(wr[(kbase + 0) * CR + n], wr[(kbase + 1) * CR + n]);
        uint32_t pk1 = pkbf(wr[(kbase + 2) * CR + n], wr[(kbase + 3) * CR + n]);
        uint32_t pk2 = pkbf(wr[(kbase + 4) * CR + n], wr[(kbase + 5) * CR + n]);
        uint32_t pk3 = pkbf(wr[(kbase + 6) * CR + n], wr[(kbase + 7) * CR + n]);
        *(uint4*)(wrl + run * 8) = make_uint4(pk0, pk1, pk2, pk3);
    }
    __syncthreads();

    int mt = blockIdx.x * 4 + w;                 // 784 row-tiles of 16 pixels
    int pix = mt * 16 + (lane & 15);             // A-frag: m = lane&15
    int ko = (lane >> 4) * 8;                    // k-offset within 32-block
    const float* xrow = x + (size_t)pix * C_ + ko;
    f32x4 acc[4] = {{0,0,0,0},{0,0,0,0},{0,0,0,0},{0,0,0,0}};
    for (int kb = 0; kb < 8; ++kb) {             // K = 256 in steps of 32
        float4 a0 = *(const float4*)(xrow + kb * 32);
        float4 a1 = *(const float4*)(xrow + kb * 32 + 4);
        U4V af;
        af.u = make_uint4(pkbf(a0.x, a0.y), pkbf(a0.z, a0.w),
                          pkbf(a1.x, a1.y), pkbf(a1.z, a1.w));
        // bf16 copy of x for K2 staging
        *(uint4*)(xbf + (size_t)pix * C_ + ko + kb * 32) = af.u;
        const uint16_t* wb = wrl + kb * 2048 + lane * 8;
        #pragma unroll
        for (int nb = 0; nb < 4; ++nb) {
            bf16x8 bf_ = *(const bf16x8*)(wb + nb * 512);   // ds_read_b128
            acc[nb] = __builtin_amdgcn_mfma_f32_16x16x32_bf16(af.v, bf_, acc[nb], 0, 0, 0);
        }
    }
    // C layout: col=lane&15 (channel), row=(lane>>4)*4+reg (pixel). BN inline (same ops as old k0).
    int rq = (lane >> 4) * 4;
    #pragma unroll
    for (int nb = 0; nb < 4; ++nb) {
        int d = nb * 16 + (lane & 15);
        float s  = gamma[d] * rsqrtf(var[d] + 1e-3f);
        float sh = beta[d] - mean[d] * s;
        #pragma unroll
        for (int rg = 0; rg < 4; ++rg) {
            float v = fmaf(acc[nb][rg], s, sh);
            v = v > 0.f ? v : 0.f;
            r[(size_t)(mt * 16 + rq + rg) * CR + d] = (uint16_t)f2bf(v);
        }
    }
}

// ---------- K2: kgen (MFMA) + involution, one block per (tile, group, batch) ----------
#define TS   14          // output tile edge
#define HS   20          // TS + KS - 1
#define XSW  16          // u16 per LDS position slot (16 ch; 32B slot, 16B aligned)
#define KGW  56          // u16 per kg row: 7 kh * 8 slots (7 taps + 1 pad), per-kh uint4 aligned

__global__ __launch_bounds__(256, 4) void k2_involution(
        const uint16_t* __restrict__ xbf, const uint16_t* __restrict__ r,
        const float* __restrict__ wspan, const float* __restrict__ bspan,
        float* __restrict__ out) {
    __shared__ __align__(16) uint16_t xs[HS * HS * XSW];   // 12800 B
    __shared__ __align__(16) uint16_t kg[196 * KGW];       // 21952 B  (34.75 KB -> 4 blocks/CU)

    int tid  = threadIdx.x;
    int tile = blockIdx.x, g = blockIdx.y, b = blockIdx.z;
    int ty0 = (tile >> 2) * TS, tx0 = (tile & 3) * TS;

    // ---- stage x group-slice (with halo) into LDS: raw bf16 ----
    #pragma unroll
    for (int pass = 0; pass < 2; ++pass) {
        int i = tid + pass * 256;
        if (i < HS * HS) {
            int py = i / HS, px = i % HS;
            int gy = ty0 + py - PADR, gx = tx0 + px - PADR;
            uint4 wA = make_uint4(0, 0, 0, 0), wB = wA;
            if (gy >= 0 && gy < H_ && gx >= 0 && gx < W_) {
                const uint16_t* xp = xbf + (((size_t)(b * H_ + gy)) * W_ + gx) * C_ + g * CG;
                wA = *(const uint4*)(xp);
                wB = *(const uint4*)(xp + 8);
            }
            uint16_t* dst = xs + i * XSW;
            *(uint4*)(dst + 0) = wA;
            *(uint4*)(dst + 8) = wB;
        }
    }

    // ---- gather this group's w_span B-frags from global fp32 (replaces old k0 wpp) ----
    int lane = tid & 63, w = tid >> 6;
    bf16x8 bfr[2][4];
    #pragma unroll
    for (int kb = 0; kb < 2; ++kb) {
        #pragma unroll
        for (int nb = 0; nb < 4; ++nb) {
            int n = nb * 16 + (lane & 15);
            int kbase = kb * 32 + (lane >> 4) * 8;
            U4V u;
            if (n < KK) {
                const float* wp = wspan + g * KK + n;
                u.u = make_uint4(
                    pkbf(wp[(size_t)(kbase + 0) * (KK * G_)], wp[(size_t)(kbase + 1) * (KK * G_)]),
                    pkbf(wp[(size_t)(kbase + 2) * (KK * G_)], wp[(size_t)(kbase + 3) * (KK * G_)]),
                    pkbf(wp[(size_t)(kbase + 4) * (KK * G_)], wp[(size_t)(kbase + 5) * (KK * G_)]),
                    pkbf(wp[(size_t)(kbase + 6) * (KK * G_)], wp[(size_t)(kbase + 7) * (KK * G_)]));
            } else {
                u.u = make_uint4(0, 0, 0, 0);
            }
            bfr[kb][nb] = u.v;
        }
    }
    float bias[4];
    #pragma unroll
    for (int nb = 0; nb < 4; ++nb) {
        int n = nb * 16 + (lane & 15);
        bias[nb] = (n < KK) ? bspan[g * KK + n] : 0.f;
    }

    // ---- kgen via MFMA: kg(196x49) = r_tile(196x64) @ wspan_g(64x49) + bias ----
    for (int mi = 0; mi < 4; ++mi) {
        int mt = mi * 4 + w;                    // 13 row-tiles over 4 waves
        if (mt < 13) {
            int m  = mt * 16 + (lane & 15);
            int mm = m < 196 ? m : 195;         // pad rows: valid mem, ignored later
            int ly = mm / TS, lx = mm % TS;
            size_t pix = ((size_t)(b * H_ + ty0 + ly)) * W_ + (tx0 + lx);
            const uint16_t* rp = r + pix * CR + (lane >> 4) * 8;
            bf16x8 a0 = *(const bf16x8*)(rp);
            bf16x8 a1 = *(const bf16x8*)(rp + 32);
            f32x4 acc[4];
            #pragma unroll
            for (int nb = 0; nb < 4; ++nb)
                acc[nb] = (f32x4){bias[nb], bias[nb], bias[nb], bias[nb]};
            #pragma unroll
            for (int nb = 0; nb < 4; ++nb) {
                acc[nb] = __builtin_amdgcn_mfma_f32_16x16x32_bf16(a0, bfr[0][nb], acc[nb], 0, 0, 0);
                acc[nb] = __builtin_amdgcn_mfma_f32_16x16x32_bf16(a1, bfr[1][nb], acc[nb], 0, 0, 0);
            }
            int row = mt * 16 + (lane >> 4) * 4;
            if (row < 196) {
                #pragma unroll
                for (int nb = 0; nb < 4; ++nb) {
                    int n = nb * 16 + (lane & 15);
                    if (n < KK) {
                        int slot = n + n / 7;   // per-kh padded: kh*8 + kw
                        #pragma unroll
                        for (int rg = 0; rg < 4; ++rg)
                            kg[(row + rg) * KGW + slot] = (uint16_t)f2bf(acc[nb][rg]);
                    }
                }
            }
        }
    }
    __syncthreads();

    // ---- involution: 196 threads = (pixel-pair, 8-ch half); adjacent px share xs reads ----
    if (tid < 196) {
        int p = tid >> 1, h = tid & 1;          // pair 0..97, channel half 0/1
        int ty = p / 7, tx = (p % 7) * 2;
        const uint16_t* kgL = kg + (ty * TS + tx) * KGW;
        const uint16_t* kgR = kgL + KGW;

        f32x2 accL[4] = {{0,0},{0,0},{0,0},{0,0}};
        f32x2 accR[4] = {{0,0},{0,0},{0,0},{0,0}};
        #pragma unroll
        for (int kh = 0; kh < KS; ++kh) {
            uint4 aL = *(const uint4*)(kgL + kh * 8);   // taps kh*7..kh*7+6 (+pad)
            uint4 aR = *(const uint4*)(kgR + kh * 8);
            const uint32_t kwL[4] = {aL.x, aL.y, aL.z, aL.w};
            const uint32_t kwR[4] = {aR.x, aR.y, aR.z, aR.w};
            const uint16_t* xrow = xs + ((ty + kh) * HS + tx) * XSW + h * 8;
            #pragma unroll
            for (int j = 0; j < 8; ++j) {       // union of both 7-tap windows
                uint4 xw = *(const uint4*)(xrow + j * XSW);   // 8 bf16 channels
                float kvL = 0.f, kvR = 0.f;
                if (j < 7) kvL = (j & 1) ? bhi(kwL[j >> 1]) : blo(kwL[j >> 1]);
                if (j > 0) { int t = j - 1; kvR = (t & 1) ? bhi(kwR[t >> 1]) : blo(kwR[t >> 1]); }
                f32x2 kL = {kvL, kvL}, kR = {kvR, kvR};
                f32x2 x0 = {blo(xw.x), bhi(xw.x)};
                f32x2 x1 = {blo(xw.y), bhi(xw.y)};
                f32x2 x2 = {blo(xw.z), bhi(xw.z)};
                f32x2 x3 = {blo(xw.w), bhi(xw.w)};
                accL[0] = __builtin_elementwise_fma(kL, x0, accL[0]);
                accL[1] = __builtin_elementwise_fma(kL, x1, accL[1]);
                accL[2] = __builtin_elementwise_fma(kL, x2, accL[2]);
                accL[3] = __builtin_elementwise_fma(kL, x3, accL[3]);
                accR[0] = __builtin_elementwise_fma(kR, x0, accR[0]);
                accR[1] = __builtin_elementwise_fma(kR, x1, accR[1]);
                accR[2] = __builtin_elementwise_fma(kR, x2, accR[2]);
                accR[3] = __builtin_elementwise_fma(kR, x3, accR[3]);
            }
        }
        size_t pixL = ((size_t)(b * H_ + ty0 + ty)) * W_ + (tx0 + tx);
        float* opL = out + pixL * C_ + g * CG + h * 8;
        float* opR = opL + C_;
        *(float4*)(opL + 0) = make_float4(accL[0].x, accL[0].y, accL[1].x, accL[1].y);
        *(float4*)(opL + 4) = make_float4(accL[2].x, accL[2].y, accL[3].x, accL[3].y);
        *(float4*)(opR + 0) = make_float4(accR[0].x, accR[0].y, accR[1].x, accR[1].y);
        *(float4*)(opR + 4) = make_float4(accR[2].x, accR[2].y, accR[3].x, accR[3].y);
    }
}

extern "C" void kernel_launch(void* const* d_in, const int* in_sizes, int n_in,
                              void* d_out, int out_size, void* d_ws, size_t ws_size,
                              hipStream_t stream) {
    const float* x        = (const float*)d_in[0];
    const float* w_reduce = (const float*)d_in[1];
    const float* gamma    = (const float*)d_in[2];
    const float* beta     = (const float*)d_in[3];
    const float* mean     = (const float*)d_in[4];
    const float* var      = (const float*)d_in[5];
    const float* w_span   = (const float*)d_in[6];
    const float* b_span   = (const float*)d_in[7];
    float* out = (float*)d_out;

    uint8_t* ws = (uint8_t*)d_ws;
    uint16_t* r_ws = (uint16_t*)(ws + 0);          // 1605632 B
    uint16_t* xbf  = (uint16_t*)(ws + 1605632);    // 6422528 B

    hipLaunchKernelGGL(k1_reduce, dim3(NPX / 64), dim3(256), 0, stream,
                       x, w_reduce, gamma, beta, mean, var, r_ws, xbf);
    hipLaunchKernelGGL(k2_involution, dim3(16, 16, B_), dim3(256), 0, stream,
                       xbf, r_ws, w_span, b_span, out);
}